// Round 3
// baseline (5545.861 us; speedup 1.0000x reference)
//
#include <hip/hip_runtime.h>
#include <math.h>

#define WAYS 5
#define NQN 4096
#define NBATCH (NQN*WAYS)

// workspace float offsets (same as round 2 — proven to fit ws)
#define WS_SC 0         // 5*25*64 spt centered [w][i][c]
#define WS_RS 8000      // 125 inv l2 norms
#define WS_SP 8125      // 125 proj
#define WS_QM 8250      // 102400 qry per-token channel mean [q][j]
#define WS_QR 110650    // 102400 qry inv l2 norm
#define WS_TP 213050    // 102400 qry proj

__global__ void prep_spt(const float* __restrict__ spt, const float* __restrict__ proj_w,
                         const float* __restrict__ proj_b, float* __restrict__ ws) {
    int tid = threadIdx.x;
    if (tid >= 125) return;
    int w = tid / 25, i = tid % 25;
    const float* base = spt + w * 1600 + i;
    float s = 0.f;
    for (int c = 0; c < 64; c++) s += base[c * 25];
    float m = s * (1.f / 64.f);
    float ss = 0.f, pj = 0.f;
    for (int c = 0; c < 64; c++) {
        float v = base[c * 25] - m;
        ss += v * v; pj += v * proj_w[c];
        ws[WS_SC + (w * 25 + i) * 64 + c] = v;
    }
    ws[WS_RS + w * 25 + i] = rsqrtf(ss + 1e-6f);
    ws[WS_SP + w * 25 + i] = pj + proj_b[0];
}

__global__ void prep_qry(const float* __restrict__ qry, const float* __restrict__ proj_w,
                         const float* __restrict__ proj_b, float* __restrict__ ws) {
    int idx = blockIdx.x * 256 + threadIdx.x;
    if (idx >= NQN * 25) return;
    int q = idx / 25, j = idx % 25;
    const float* base = qry + q * 1600 + j;
    float s = 0.f;
    for (int c = 0; c < 64; c++) s += base[c * 25];
    float m = s * (1.f / 64.f);
    float ss = 0.f, pj = 0.f;
    for (int c = 0; c < 64; c++) {
        float v = base[c * 25] - m;
        ss += v * v; pj += v * proj_w[c];
    }
    ws[WS_QM + idx] = m;
    ws[WS_QR + idx] = rsqrtf(ss + 1e-6f);
    ws[WS_TP + idx] = pj + proj_b[0];
}

// A in LDS (stride SA), W in global row-major [N][WN] over k (f2 loads; K even).
// O[m*SO+n] {=|+=} act( scale * sum_k A.. * W.. + bias[n] ). GUARD: skip store for n>=N
// (needed for ADD with clamped tail); without GUARD, clamped dup-stores are benign.
template<int M, int N, int K, int TM, int TN, int SA, int WN, int SO,
         bool ADD, bool GELU, bool GUARD>
__device__ __forceinline__ void mmg(const float* __restrict__ A, const float* __restrict__ W,
                                    const float* __restrict__ bias, float* __restrict__ O,
                                    float scale, int tid) {
    static_assert(M % TM == 0 && K % 2 == 0, "shape");
    constexpr int GM = M / TM;
    constexpr int GN = (N + TN - 1) / TN;
    for (int v = tid; v < GM * GN; v += 64) {
        const int m0 = (v / GN) * TM, n0 = (v % GN) * TN;
        float acc[TM][TN];
#pragma unroll
        for (int a = 0; a < TM; a++)
#pragma unroll
            for (int c = 0; c < TN; c++) acc[a][c] = 0.f;
#pragma unroll
        for (int k = 0; k < K; k += 2) {
            float2 av[TM], wv[TN];
#pragma unroll
            for (int a = 0; a < TM; a++) av[a] = *(const float2*)(A + (m0 + a) * SA + k);
#pragma unroll
            for (int c = 0; c < TN; c++) {
                int nn = n0 + c; if (nn > N - 1) nn = N - 1;
                wv[c] = *(const float2*)(W + nn * WN + k);
            }
#pragma unroll
            for (int a = 0; a < TM; a++)
#pragma unroll
                for (int c = 0; c < TN; c++) {
                    acc[a][c] += av[a].x * wv[c].x;
                    acc[a][c] += av[a].y * wv[c].y;
                }
        }
#pragma unroll
        for (int a = 0; a < TM; a++)
#pragma unroll
            for (int c = 0; c < TN; c++) {
                int nn = n0 + c;
                if (GUARD && nn >= N) continue;
                int ns = nn > N - 1 ? N - 1 : nn;
                float r = acc[a][c] * scale + (bias ? bias[ns] : 0.f);
                if (GELU) r = 0.5f * r * (1.f + erff(r * 0.70710678118654752f));
                if (ADD) O[(m0 + a) * SO + ns] += r; else O[(m0 + a) * SO + ns] = r;
            }
    }
}

__device__ __forceinline__ void ln_row(const float* __restrict__ x, float* __restrict__ h,
                                       const float* __restrict__ g, const float* __restrict__ bb) {
    float s = 0.f;
#pragma unroll
    for (int e = 0; e < 26; e++) s += x[e];
    float m = s * (1.f / 26.f);
    float vv = 0.f;
#pragma unroll
    for (int e = 0; e < 26; e++) { float d = x[e] - m; vv += d * d; }
    float r = rsqrtf(vv * (1.f / 26.f) + 1e-6f);
#pragma unroll
    for (int e = 0; e < 26; e++) h[e] = (x[e] - m) * r * g[e] + bb[e];
}

// One pre-LN transformer block, wave-synchronous (block == 1 wave == 64 lanes).
__device__ void xblock(float* __restrict__ xm, float* __restrict__ buf,
                       float* __restrict__ scratch,
                       const float* __restrict__ qkv_w, const float* __restrict__ qkv_b,
                       const float* __restrict__ attn_w, const float* __restrict__ attn_b,
                       const float* __restrict__ ln1_g, const float* __restrict__ ln1_b,
                       const float* __restrict__ ln2_g, const float* __restrict__ ln2_b,
                       const float* __restrict__ fc1_w, const float* __restrict__ fc1_b,
                       const float* __restrict__ fc2_w, const float* __restrict__ fc2_b,
                       int tid) {
    if (tid < 25) ln_row(xm + tid * 26, scratch + tid * 26, ln1_g, ln1_b);
    __syncthreads();
    // qkv: (25x26)@(26x78) -> buf [t][78] = [q0 q1 | k0 k1 | v0 v1]
    mmg<25, 78, 26, 5, 3, 26, 26, 78, false, false, false>(scratch, qkv_w, qkv_b, buf, 1.f, tid);
    __syncthreads();
    const float SC = 0.27735009811261457f;  // 13^-0.5
    for (int h = 0; h < 2; h++) {
        // scores[i][j] = q_i . k_j, K=13 -> scratch (h is dead)
        for (int v = tid; v < 65; v += 64) {
            int m0 = (v / 13) * 5, j0 = (v % 13) * 2;
            int j1 = j0 + 1 > 24 ? 24 : j0 + 1;
            float acc[5][2] = {};
#pragma unroll
            for (int k = 0; k < 13; k++) {
                float k0 = buf[j0 * 78 + 26 + h * 13 + k];
                float k1 = buf[j1 * 78 + 26 + h * 13 + k];
#pragma unroll
                for (int a = 0; a < 5; a++) {
                    float qv = buf[(m0 + a) * 78 + h * 13 + k];
                    acc[a][0] += qv * k0; acc[a][1] += qv * k1;
                }
            }
#pragma unroll
            for (int a = 0; a < 5; a++) {
                scratch[(m0 + a) * 25 + j0] = acc[a][0] * SC;
                scratch[(m0 + a) * 25 + j1] = acc[a][1] * SC;
            }
        }
        __syncthreads();
        if (tid < 25) {  // softmax over keys
            float* row = scratch + tid * 25;
            float mx = row[0];
            for (int j = 1; j < 25; j++) mx = fmaxf(mx, row[j]);
            float s = 0.f;
            for (int j = 0; j < 25; j++) { float e = __expf(row[j] - mx); row[j] = e; s += e; }
            float inv = 1.f / s;
            for (int j = 0; j < 25; j++) row[j] *= inv;
        }
        __syncthreads();
        // o_h = P @ v_h -> overwrite q_h slots (dead): buf[t*78 + h*13 + n]
        for (int v = tid; v < 35; v += 64) {
            int m0 = (v / 7) * 5, n0 = (v % 7) * 2;
            int n1 = n0 + 1 > 12 ? 12 : n0 + 1;
            float acc[5][2] = {};
#pragma unroll
            for (int k = 0; k < 25; k++) {
                float v0 = buf[k * 78 + 52 + h * 13 + n0];
                float v1 = buf[k * 78 + 52 + h * 13 + n1];
#pragma unroll
                for (int a = 0; a < 5; a++) {
                    float p = scratch[(m0 + a) * 25 + k];
                    acc[a][0] += p * v0; acc[a][1] += p * v1;
                }
            }
#pragma unroll
            for (int a = 0; a < 5; a++) {
                buf[(m0 + a) * 78 + h * 13 + n0] = acc[a][0];
                buf[(m0 + a) * 78 + h * 13 + n1] = acc[a][1];
            }
        }
        __syncthreads();
    }
    // attn proj + residual: oatt = buf[t][0..26]
    mmg<25, 26, 26, 5, 2, 78, 26, 26, true, false, false>(buf, attn_w, attn_b, xm, 1.f, tid);
    __syncthreads();
    if (tid < 25) ln_row(xm + tid * 26, scratch + tid * 26, ln2_g, ln2_b);
    __syncthreads();
    // MLP in two N-halves; hidden lives over dead k/v region buf[t*78+26 .. +78]
    for (int hh = 0; hh < 2; hh++) {
        mmg<25, 52, 26, 5, 4, 26, 26, 78, false, true, false>(
            scratch, fc1_w + hh * 52 * 26, fc1_b + hh * 52, buf + 26, 1.f, tid);
        __syncthreads();
        mmg<25, 26, 52, 5, 2, 78, 104, 26, true, false, false>(
            buf + 26, fc2_w + hh * 52, hh == 0 ? fc2_b : nullptr, xm, 1.f, tid);
        __syncthreads();
    }
}

__global__ void __launch_bounds__(64, 3)
fused_kernel(const float* __restrict__ qry, const float* __restrict__ ws,
             const float* __restrict__ pos_x, const float* __restrict__ pos_y,
             const float* __restrict__ qkv_w, const float* __restrict__ qkv_b,
             const float* __restrict__ attn_w, const float* __restrict__ attn_b,
             const float* __restrict__ ln1_g, const float* __restrict__ ln1_b,
             const float* __restrict__ ln2_g, const float* __restrict__ ln2_b,
             const float* __restrict__ fc1_w, const float* __restrict__ fc1_b,
             const float* __restrict__ fc2_w, const float* __restrict__ fc2_b,
             const float* __restrict__ dec_w, const float* __restrict__ dec_b,
             float* __restrict__ out) {
    __shared__ __align__(16) float xm[656];
    __shared__ __align__(16) float corrm[640];
    __shared__ __align__(16) float buf[1952];     // qkv/oatt/hidden; corr staging (2x 25x36)
    __shared__ __align__(16) float scratch[656];  // h / scores / dec1 / gnorm-P
    __shared__ float asv[25], aqv[25];

    const int b = blockIdx.x, q = b / WAYS, w = b % WAYS, tid = threadIdx.x;

    // ---- corr = s_norm @ t_norm^T, K=64 in two 32-halves staged into buf ----
    {
        float acc[2][5][2] = {};
        for (int half = 0; half < 2; half++) {
            const int c0 = half * 32;
            // stage spt half (normalized): buf[i*36 + cc], f4
            for (int r = 0; r < 4; r++) {
                int e4 = tid + r * 64;
                if (e4 < 200) {
                    int i = e4 >> 3, cc4 = (e4 & 7) * 4;
                    float4 s = *(const float4*)(ws + WS_SC + w * 1600 + i * 64 + c0 + cc4);
                    float rs = ws[WS_RS + w * 25 + i];
                    float4 o; o.x = s.x * rs; o.y = s.y * rs; o.z = s.z * rs; o.w = s.w * rs;
                    *(float4*)(buf + i * 36 + cc4) = o;
                }
            }
            // stage qry half (centered+normalized, transposed): buf[900 + j*36 + cc]
            for (int r = 0; r < 13; r++) {
                int e = tid + r * 64;
                if (e < 800) {
                    int j = e >> 5, cc = e & 31;
                    float qm = ws[WS_QM + q * 25 + j], qr = ws[WS_QR + q * 25 + j];
                    buf[900 + j * 36 + cc] = (qry[q * 1600 + (c0 + cc) * 25 + j] - qm) * qr;
                }
            }
            __syncthreads();
            for (int it = 0; it < 2; it++) {
                int v = tid + it * 64;
                if (v < 65) {
                    int m0 = (v / 13) * 5, j0 = (v % 13) * 2;
                    int j1 = j0 + 1 > 24 ? 24 : j0 + 1;
#pragma unroll
                    for (int kk = 0; kk < 32; kk += 4) {
                        float4 b0 = *(const float4*)(buf + 900 + j0 * 36 + kk);
                        float4 b1 = *(const float4*)(buf + 900 + j1 * 36 + kk);
#pragma unroll
                        for (int a = 0; a < 5; a++) {
                            float4 a4 = *(const float4*)(buf + (m0 + a) * 36 + kk);
                            acc[it][a][0] += a4.x * b0.x + a4.y * b0.y + a4.z * b0.z + a4.w * b0.w;
                            acc[it][a][1] += a4.x * b1.x + a4.y * b1.y + a4.z * b1.z + a4.w * b1.w;
                        }
                    }
                }
            }
            __syncthreads();  // before restaging / reuse of buf
        }
        for (int it = 0; it < 2; it++) {
            int v = tid + it * 64;
            if (v < 65) {
                int m0 = (v / 13) * 5, j0 = (v % 13) * 2;
                int j1 = j0 + 1 > 24 ? 24 : j0 + 1;
#pragma unroll
                for (int a = 0; a < 5; a++) {
                    corrm[(m0 + a) * 25 + j0] = acc[it][a][0];
                    corrm[(m0 + a) * 25 + j1] = acc[it][a][1];
                }
            }
        }
        __syncthreads();
    }

    // ---- x1: rows = qry tokens; [corr^T | tp] + pos ----
    for (int r = 0; r < 11; r++) {
        int e = tid + r * 64;
        if (e < 650) {
            int t = e / 26, d = e % 26;
            float p = (d < 13) ? pos_x[(t % 5) * 13 + d] : pos_y[(t / 5) * 13 + (d - 13)];
            float base = (d < 25) ? corrm[d * 25 + t] : ws[WS_TP + q * 25 + t];
            xm[e] = base + p;
        }
    }
    __syncthreads();

    xblock(xm, buf, scratch, qkv_w, qkv_b, attn_w, attn_b, ln1_g, ln1_b, ln2_g, ln2_b,
           fc1_w, fc1_b, fc2_w, fc2_b, tid);

    // dec1 -> scratch[t][m]
    mmg<25, 25, 26, 5, 2, 26, 26, 25, false, false, false>(xm, dec_w, dec_b, scratch, 1.f, tid);
    __syncthreads();

    // ---- x2: rows = spt tokens; [dec1^T + corr | sp] + pos ----
    for (int r = 0; r < 11; r++) {
        int e = tid + r * 64;
        if (e < 650) {
            int t = e / 26, d = e % 26;
            float p = (d < 13) ? pos_x[(t % 5) * 13 + d] : pos_y[(t / 5) * 13 + (d - 13)];
            float base = (d < 25) ? (scratch[d * 25 + t] + corrm[t * 25 + d]) : ws[WS_SP + w * 25 + t];
            xm[e] = base + p;
        }
    }
    __syncthreads();

    xblock(xm, buf, scratch, qkv_w, qkv_b, attn_w, attn_b, ln1_g, ln1_b, ln2_g, ln2_b,
           fc1_w, fc1_b, fc2_w, fc2_b, tid);

    // dec2, ADD into corrm -> refined (GUARD: no double-add on clamped tail)
    mmg<25, 25, 26, 5, 2, 26, 26, 25, true, false, true>(xm, dec_w, dec_b, corrm, 1.f, tid);
    __syncthreads();

    // ---- attn_s: per column j, gnorm+softmax over i; P -> scratch ----
    if (tid < 25) {
        int j = tid;
        float s = 0.f;
        for (int i = 0; i < 25; i++) s += corrm[i * 25 + j];
        float m = s * 0.04f;
        float ss = 0.f;
        for (int i = 0; i < 25; i++) { float d = corrm[i * 25 + j] - m; ss += d * d; }
        float rinv = rsqrtf(ss * (1.f / 24.f) + 1e-5f) * 0.2f;   // /T_ATTN
        float mx = -1e30f;
        for (int i = 0; i < 25; i++) { float z = (corrm[i * 25 + j] - m) * rinv; scratch[i * 25 + j] = z; mx = fmaxf(mx, z); }
        float se = 0.f;
        for (int i = 0; i < 25; i++) { float e2 = __expf(scratch[i * 25 + j] - mx); scratch[i * 25 + j] = e2; se += e2; }
        float inv = 1.f / se;
        for (int i = 0; i < 25; i++) scratch[i * 25 + j] *= inv;
    }
    __syncthreads();
    if (tid < 25) {  // row sums * 1/25  (spt side pools the CENTERED features from ws)
        int i = tid; float s = 0.f;
        for (int j = 0; j < 25; j++) s += scratch[i * 25 + j];
        asv[i] = s * 0.04f;
    }
    __syncthreads();
    // ---- attn_q: per row i, gnorm+softmax over j; P -> scratch ----
    if (tid < 25) {
        int i = tid;
        float s = 0.f;
        for (int j = 0; j < 25; j++) s += corrm[i * 25 + j];
        float m = s * 0.04f;
        float ss = 0.f;
        for (int j = 0; j < 25; j++) { float d = corrm[i * 25 + j] - m; ss += d * d; }
        float rinv = rsqrtf(ss * (1.f / 24.f) + 1e-5f) * 0.2f;
        float mx = -1e30f;
        for (int j = 0; j < 25; j++) { float z = (corrm[i * 25 + j] - m) * rinv; scratch[i * 25 + j] = z; mx = fmaxf(mx, z); }
        float se = 0.f;
        for (int j = 0; j < 25; j++) { float e2 = __expf(scratch[i * 25 + j] - mx); scratch[i * 25 + j] = e2; se += e2; }
        float inv = 1.f / se;
        for (int j = 0; j < 25; j++) scratch[i * 25 + j] *= inv;
    }
    __syncthreads();
    if (tid < 25) {
        int j = tid; float s = 0.f;
        for (int i = 0; i < 25; i++) s += scratch[i * 25 + j];
        aqv[j] = s * 0.04f;
    }
    __syncthreads();

    // ---- pooling + cosine: lane = channel c (64 lanes), features from global ----
    {
        int c = tid;
        float sp = 0.f;
        for (int i = 0; i < 25; i++)
            sp += asv[i] * ws[WS_SC + w * 1600 + i * 64 + c];   // centered spt
        float qp = 0.f;
        const float* qbase = qry + q * 1600 + c * 25;
        for (int j = 0; j < 25; j++)
            qp += aqv[j] * (qbase[j] - ws[WS_QM + q * 25 + j]); // centered qry
        float dp = sp * qp, a2 = sp * sp, b2 = qp * qp;
        for (int off = 32; off > 0; off >>= 1) {
            dp += __shfl_xor(dp, off);
            a2 += __shfl_xor(a2, off);
            b2 += __shfl_xor(b2, off);
        }
        if (tid == 0) {
            float n1 = fmaxf(sqrtf(a2), 1e-8f);
            float n2 = fmaxf(sqrtf(b2), 1e-8f);
            out[b] = dp / (n1 * n2) * 5.f;   // /TEMP
        }
    }
}

extern "C" void kernel_launch(void* const* d_in, const int* in_sizes, int n_in,
                              void* d_out, int out_size, void* d_ws, size_t ws_size,
                              hipStream_t stream) {
    const float* spt    = (const float*)d_in[0];
    const float* qry    = (const float*)d_in[1];
    const float* proj_w = (const float*)d_in[2];
    const float* proj_b = (const float*)d_in[3];
    const float* pos_x  = (const float*)d_in[4];
    const float* pos_y  = (const float*)d_in[5];
    const float* ln1_g  = (const float*)d_in[6];
    const float* ln1_b  = (const float*)d_in[7];
    const float* qkv_w  = (const float*)d_in[8];
    const float* qkv_b  = (const float*)d_in[9];
    const float* attn_w = (const float*)d_in[10];
    const float* attn_b = (const float*)d_in[11];
    const float* ln2_g  = (const float*)d_in[12];
    const float* ln2_b  = (const float*)d_in[13];
    const float* fc1_w  = (const float*)d_in[14];
    const float* fc1_b  = (const float*)d_in[15];
    const float* fc2_w  = (const float*)d_in[16];
    const float* fc2_b  = (const float*)d_in[17];
    const float* dec_w  = (const float*)d_in[18];
    const float* dec_b  = (const float*)d_in[19];
    float* ws  = (float*)d_ws;
    float* out = (float*)d_out;

    prep_spt<<<1, 128, 0, stream>>>(spt, proj_w, proj_b, ws);
    prep_qry<<<(NQN * 25 + 255) / 256, 256, 0, stream>>>(qry, proj_w, proj_b, ws);
    fused_kernel<<<NBATCH, 64, 0, stream>>>(qry, ws, pos_x, pos_y, qkv_w, qkv_b, attn_w, attn_b,
                                            ln1_g, ln1_b, ln2_g, ln2_b, fc1_w, fc1_b,
                                            fc2_w, fc2_b, dec_w, dec_b, out);
}

// Round 4
// 5244.030 us; speedup vs baseline: 1.0576x; 1.0576x over previous
//
#include <hip/hip_runtime.h>
#include <math.h>

#define WAYS 5
#define NQN 4096
#define NBATCH (NQN*WAYS)

// workspace float offsets
#define WS_SC 0         // 5*25*64 spt centered [w][i][c]
#define WS_RS 8000      // 125 inv l2 norms
#define WS_SP 8125      // 125 proj
#define WS_QM 8250      // 102400 qry per-token channel mean [q][j]
#define WS_QR 110650    // 102400 qry inv l2 norm
#define WS_TP 213050    // 102400 qry proj

__global__ void prep_spt(const float* __restrict__ spt, const float* __restrict__ proj_w,
                         const float* __restrict__ proj_b, float* __restrict__ ws) {
    int tid = threadIdx.x;
    if (tid >= 125) return;
    int w = tid / 25, i = tid % 25;
    const float* base = spt + w * 1600 + i;
    float s = 0.f;
    for (int c = 0; c < 64; c++) s += base[c * 25];
    float m = s * (1.f / 64.f);
    float ss = 0.f, pj = 0.f;
    for (int c = 0; c < 64; c++) {
        float v = base[c * 25] - m;
        ss += v * v; pj += v * proj_w[c];
        ws[WS_SC + (w * 25 + i) * 64 + c] = v;
    }
    ws[WS_RS + w * 25 + i] = rsqrtf(ss + 1e-6f);
    ws[WS_SP + w * 25 + i] = pj + proj_b[0];
}

__global__ void prep_qry(const float* __restrict__ qry, const float* __restrict__ proj_w,
                         const float* __restrict__ proj_b, float* __restrict__ ws) {
    int idx = blockIdx.x * 256 + threadIdx.x;
    if (idx >= NQN * 25) return;
    int q = idx / 25, j = idx % 25;
    const float* base = qry + q * 1600 + j;
    float s = 0.f;
    for (int c = 0; c < 64; c++) s += base[c * 25];
    float m = s * (1.f / 64.f);
    float ss = 0.f, pj = 0.f;
    for (int c = 0; c < 64; c++) {
        float v = base[c * 25] - m;
        ss += v * v; pj += v * proj_w[c];
    }
    ws[WS_QM + idx] = m;
    ws[WS_QR + idx] = rsqrtf(ss + 1e-6f);
    ws[WS_TP + idx] = pj + proj_b[0];
}

// A in LDS (stride SA), W in global row-major [N][WN] over k (f2 loads; K even).
// O[m*SO+n] {=|+=} act( scale * sum_k A.. * W.. + bias[n] ). GUARD: skip store for n>=N.
template<int M, int N, int K, int TM, int TN, int SA, int WN, int SO,
         bool ADD, bool GELU, bool GUARD>
__device__ __forceinline__ void mmg(const float* __restrict__ A, const float* __restrict__ W,
                                    const float* __restrict__ bias, float* __restrict__ O,
                                    float scale, int tid) {
    static_assert(M % TM == 0 && K % 2 == 0, "shape");
    constexpr int GM = M / TM;
    constexpr int GN = (N + TN - 1) / TN;
    for (int v = tid; v < GM * GN; v += 64) {
        const int m0 = (v / GN) * TM, n0 = (v % GN) * TN;
        float acc[TM][TN];
#pragma unroll
        for (int a = 0; a < TM; a++)
#pragma unroll
            for (int c = 0; c < TN; c++) acc[a][c] = 0.f;
#pragma unroll
        for (int k = 0; k < K; k += 2) {
            float2 av[TM], wv[TN];
#pragma unroll
            for (int a = 0; a < TM; a++) av[a] = *(const float2*)(A + (m0 + a) * SA + k);
#pragma unroll
            for (int c = 0; c < TN; c++) {
                int nn = n0 + c; if (nn > N - 1) nn = N - 1;
                wv[c] = *(const float2*)(W + nn * WN + k);
            }
#pragma unroll
            for (int a = 0; a < TM; a++)
#pragma unroll
                for (int c = 0; c < TN; c++) {
                    acc[a][c] += av[a].x * wv[c].x;
                    acc[a][c] += av[a].y * wv[c].y;
                }
        }
#pragma unroll
        for (int a = 0; a < TM; a++)
#pragma unroll
            for (int c = 0; c < TN; c++) {
                int nn = n0 + c;
                if (GUARD && nn >= N) continue;
                int ns = nn > N - 1 ? N - 1 : nn;
                float r = acc[a][c] * scale + (bias ? bias[ns] : 0.f);
                if (GELU) r = 0.5f * r * (1.f + erff(r * 0.70710678118654752f));
                if (ADD) O[(m0 + a) * SO + ns] += r; else O[(m0 + a) * SO + ns] = r;
            }
    }
}

__device__ __forceinline__ void ln_row(const float* __restrict__ x, float* __restrict__ h,
                                       const float* __restrict__ g, const float* __restrict__ bb) {
    float s = 0.f;
#pragma unroll
    for (int e = 0; e < 26; e++) s += x[e];
    float m = s * (1.f / 26.f);
    float vv = 0.f;
#pragma unroll
    for (int e = 0; e < 26; e++) { float d = x[e] - m; vv += d * d; }
    float r = rsqrtf(vv * (1.f / 26.f) + 1e-6f);
#pragma unroll
    for (int e = 0; e < 26; e++) h[e] = (x[e] - m) * r * g[e] + bb[e];
}

// One pre-LN transformer block, wave-synchronous (block == 1 wave == 64 lanes).
__device__ __forceinline__ void xblock(
        float* __restrict__ xm, float* __restrict__ buf, float* __restrict__ scratch,
        const float* __restrict__ qkv_w, const float* __restrict__ qkv_b,
        const float* __restrict__ attn_w, const float* __restrict__ attn_b,
        const float* __restrict__ ln1_g, const float* __restrict__ ln1_b,
        const float* __restrict__ ln2_g, const float* __restrict__ ln2_b,
        const float* __restrict__ fc1_w, const float* __restrict__ fc1_b,
        const float* __restrict__ fc2_w, const float* __restrict__ fc2_b, int tid) {
    if (tid < 25) ln_row(xm + tid * 26, scratch + tid * 26, ln1_g, ln1_b);
    __syncthreads();
    // qkv: (25x26)@(26x78) -> buf [t][78] = [q0 q1 | k0 k1 | v0 v1]
    mmg<25, 78, 26, 5, 3, 26, 26, 78, false, false, false>(scratch, qkv_w, qkv_b, buf, 1.f, tid);
    __syncthreads();
    const float SC = 0.27735009811261457f;  // 13^-0.5
    for (int h = 0; h < 2; h++) {
        // scores[i][j] = q_i . k_j, K=13 -> scratch
        for (int v = tid; v < 65; v += 64) {
            int m0 = (v / 13) * 5, j0 = (v % 13) * 2;
            int j1 = j0 + 1 > 24 ? 24 : j0 + 1;
            float acc[5][2] = {};
#pragma unroll
            for (int k = 0; k < 13; k++) {
                float k0 = buf[j0 * 78 + 26 + h * 13 + k];
                float k1 = buf[j1 * 78 + 26 + h * 13 + k];
#pragma unroll
                for (int a = 0; a < 5; a++) {
                    float qv = buf[(m0 + a) * 78 + h * 13 + k];
                    acc[a][0] += qv * k0; acc[a][1] += qv * k1;
                }
            }
#pragma unroll
            for (int a = 0; a < 5; a++) {
                scratch[(m0 + a) * 25 + j0] = acc[a][0] * SC;
                scratch[(m0 + a) * 25 + j1] = acc[a][1] * SC;
            }
        }
        __syncthreads();
        if (tid < 25) {  // softmax over keys
            float* row = scratch + tid * 25;
            float mx = row[0];
            for (int j = 1; j < 25; j++) mx = fmaxf(mx, row[j]);
            float s = 0.f;
            for (int j = 0; j < 25; j++) { float e = __expf(row[j] - mx); row[j] = e; s += e; }
            float inv = 1.f / s;
            for (int j = 0; j < 25; j++) row[j] *= inv;
        }
        __syncthreads();
        // o_h = P @ v_h -> overwrite q_h slots (dead): buf[t*78 + h*13 + n]
        for (int v = tid; v < 35; v += 64) {
            int m0 = (v / 7) * 5, n0 = (v % 7) * 2;
            int n1 = n0 + 1 > 12 ? 12 : n0 + 1;
            float acc[5][2] = {};
#pragma unroll
            for (int k = 0; k < 25; k++) {
                float v0 = buf[k * 78 + 52 + h * 13 + n0];
                float v1 = buf[k * 78 + 52 + h * 13 + n1];
#pragma unroll
                for (int a = 0; a < 5; a++) {
                    float p = scratch[(m0 + a) * 25 + k];
                    acc[a][0] += p * v0; acc[a][1] += p * v1;
                }
            }
#pragma unroll
            for (int a = 0; a < 5; a++) {
                buf[(m0 + a) * 78 + h * 13 + n0] = acc[a][0];
                buf[(m0 + a) * 78 + h * 13 + n1] = acc[a][1];
            }
        }
        __syncthreads();
    }
    // attn proj + residual: oatt = buf[t][0..26]
    mmg<25, 26, 26, 5, 2, 78, 26, 26, true, false, false>(buf, attn_w, attn_b, xm, 1.f, tid);
    __syncthreads();
    if (tid < 25) ln_row(xm + tid * 26, scratch + tid * 26, ln2_g, ln2_b);
    __syncthreads();
    // MLP in two N-halves; hidden over dead k/v region buf[t*78+26 .. +78]
    for (int hh = 0; hh < 2; hh++) {
        mmg<25, 52, 26, 5, 4, 26, 26, 78, false, true, false>(
            scratch, fc1_w + hh * 52 * 26, fc1_b + hh * 52, buf + 26, 1.f, tid);
        __syncthreads();
        mmg<25, 26, 52, 5, 2, 78, 104, 26, true, false, false>(
            buf + 26, fc2_w + hh * 52, hh == 0 ? fc2_b : nullptr, xm, 1.f, tid);
        __syncthreads();
    }
}

__global__ void __launch_bounds__(64, 3)
fused_kernel(const float* __restrict__ qry, const float* __restrict__ ws,
             const float* __restrict__ pos_x, const float* __restrict__ pos_y,
             const float* __restrict__ qkv_w, const float* __restrict__ qkv_b,
             const float* __restrict__ attn_w, const float* __restrict__ attn_b,
             const float* __restrict__ ln1_g, const float* __restrict__ ln1_b,
             const float* __restrict__ ln2_g, const float* __restrict__ ln2_b,
             const float* __restrict__ fc1_w, const float* __restrict__ fc1_b,
             const float* __restrict__ fc2_w, const float* __restrict__ fc2_b,
             const float* __restrict__ dec_w, const float* __restrict__ dec_b,
             float* __restrict__ out) {
    __shared__ __align__(16) float xm[656];
    __shared__ __align__(16) float corrm[640];
    __shared__ __align__(16) float buf[1952];     // tcb (25x68) during corr; qkv/oatt/hidden after
    __shared__ __align__(16) float scratch[656];  // h / scores / dec1 / gnorm-P
    __shared__ float rsv[25], qrv[25], asv[25], aqv[25];

    const int b = blockIdx.x, q = b / WAYS, w = b % WAYS, tid = threadIdx.x;

    // ---- stage RAW qry transposed into buf[j*68 + c]; coalesced linear read ----
    for (int r = 0; r < 25; r++) {
        int e = tid + r * 64;                 // 25*64 == 1600 exact
        int c = e / 25, j = e % 25;
        buf[j * 68 + c] = qry[q * 1600 + e];
    }
    if (tid < 25) {
        rsv[tid] = ws[WS_RS + w * 25 + tid];
        qrv[tid] = ws[WS_QR + q * 25 + tid];
    }
    __syncthreads();

    // ---- corr[i][j] = rs_i * qr_j * (sc_i . qraw_j)  (centering free: sum_c sc = 0) ----
    // 125 items (5 rows x 1 col), 2 rounds; acc local to loop body (no cross-barrier state).
    for (int v = tid; v < 125; v += 64) {
        int m0 = (v / 25) * 5, j = v % 25;
        const float* Bp = buf + j * 68;
        const float* Ap = ws + WS_SC + w * 1600 + m0 * 64;   // L1/L2-hot (32 KB total)
        float acc[5] = {};
#pragma unroll 4
        for (int kk = 0; kk < 64; kk += 4) {
            float4 bv = *(const float4*)(Bp + kk);
#pragma unroll
            for (int a = 0; a < 5; a++) {
                float4 av = *(const float4*)(Ap + a * 64 + kk);
                acc[a] += av.x * bv.x + av.y * bv.y + av.z * bv.z + av.w * bv.w;
            }
        }
        float qr = qrv[j];
#pragma unroll
        for (int a = 0; a < 5; a++)
            corrm[(m0 + a) * 25 + j] = acc[a] * rsv[m0 + a] * qr;
    }
    __syncthreads();

    // ---- x1: rows = qry tokens; [corr^T | tp] + pos ----
    for (int r = 0; r < 11; r++) {
        int e = tid + r * 64;
        if (e < 650) {
            int t = e / 26, d = e % 26;
            float p = (d < 13) ? pos_x[(t % 5) * 13 + d] : pos_y[(t / 5) * 13 + (d - 13)];
            float base = (d < 25) ? corrm[d * 25 + t] : ws[WS_TP + q * 25 + t];
            xm[e] = base + p;
        }
    }
    __syncthreads();

    xblock(xm, buf, scratch, qkv_w, qkv_b, attn_w, attn_b, ln1_g, ln1_b, ln2_g, ln2_b,
           fc1_w, fc1_b, fc2_w, fc2_b, tid);

    // dec1 -> scratch[t][m]
    mmg<25, 25, 26, 5, 2, 26, 26, 25, false, false, false>(xm, dec_w, dec_b, scratch, 1.f, tid);
    __syncthreads();

    // ---- x2: rows = spt tokens; [dec1^T + corr | sp] + pos ----
    for (int r = 0; r < 11; r++) {
        int e = tid + r * 64;
        if (e < 650) {
            int t = e / 26, d = e % 26;
            float p = (d < 13) ? pos_x[(t % 5) * 13 + d] : pos_y[(t / 5) * 13 + (d - 13)];
            float base = (d < 25) ? (scratch[d * 25 + t] + corrm[t * 25 + d]) : ws[WS_SP + w * 25 + t];
            xm[e] = base + p;
        }
    }
    __syncthreads();

    xblock(xm, buf, scratch, qkv_w, qkv_b, attn_w, attn_b, ln1_g, ln1_b, ln2_g, ln2_b,
           fc1_w, fc1_b, fc2_w, fc2_b, tid);

    // dec2, ADD into corrm -> refined (GUARD: no double-add on clamped tail)
    mmg<25, 25, 26, 5, 2, 26, 26, 25, true, false, true>(xm, dec_w, dec_b, corrm, 1.f, tid);
    __syncthreads();

    // ---- attn_s: per column j, gnorm+softmax over i; P -> scratch ----
    if (tid < 25) {
        int j = tid;
        float s = 0.f;
        for (int i = 0; i < 25; i++) s += corrm[i * 25 + j];
        float m = s * 0.04f;
        float ss = 0.f;
        for (int i = 0; i < 25; i++) { float d = corrm[i * 25 + j] - m; ss += d * d; }
        float rinv = rsqrtf(ss * (1.f / 24.f) + 1e-5f) * 0.2f;   // /T_ATTN
        float mx = -1e30f;
        for (int i = 0; i < 25; i++) { float z = (corrm[i * 25 + j] - m) * rinv; scratch[i * 25 + j] = z; mx = fmaxf(mx, z); }
        float se = 0.f;
        for (int i = 0; i < 25; i++) { float e2 = __expf(scratch[i * 25 + j] - mx); scratch[i * 25 + j] = e2; se += e2; }
        float inv = 1.f / se;
        for (int i = 0; i < 25; i++) scratch[i * 25 + j] *= inv;
    }
    __syncthreads();
    if (tid < 25) {
        int i = tid; float s = 0.f;
        for (int j = 0; j < 25; j++) s += scratch[i * 25 + j];
        asv[i] = s * 0.04f;
    }
    __syncthreads();
    // ---- attn_q: per row i, gnorm+softmax over j; P -> scratch ----
    if (tid < 25) {
        int i = tid;
        float s = 0.f;
        for (int j = 0; j < 25; j++) s += corrm[i * 25 + j];
        float m = s * 0.04f;
        float ss = 0.f;
        for (int j = 0; j < 25; j++) { float d = corrm[i * 25 + j] - m; ss += d * d; }
        float rinv = rsqrtf(ss * (1.f / 24.f) + 1e-5f) * 0.2f;
        float mx = -1e30f;
        for (int j = 0; j < 25; j++) { float z = (corrm[i * 25 + j] - m) * rinv; scratch[i * 25 + j] = z; mx = fmaxf(mx, z); }
        float se = 0.f;
        for (int j = 0; j < 25; j++) { float e2 = __expf(scratch[i * 25 + j] - mx); scratch[i * 25 + j] = e2; se += e2; }
        float inv = 1.f / se;
        for (int j = 0; j < 25; j++) scratch[i * 25 + j] *= inv;
    }
    __syncthreads();
    if (tid < 25) {
        int j = tid; float s = 0.f;
        for (int i = 0; i < 25; i++) s += scratch[i * 25 + j];
        aqv[j] = s * 0.04f;
    }
    __syncthreads();

    // ---- pooling + cosine: lane = channel c (64 lanes), features from global ----
    {
        int c = tid;
        float sp = 0.f;
        for (int i = 0; i < 25; i++)
            sp += asv[i] * ws[WS_SC + w * 1600 + i * 64 + c];   // centered spt
        float qp = 0.f;
        const float* qbase = qry + q * 1600 + c * 25;
        for (int j = 0; j < 25; j++)
            qp += aqv[j] * (qbase[j] - ws[WS_QM + q * 25 + j]); // centered qry
        float dp = sp * qp, a2 = sp * sp, b2 = qp * qp;
        for (int off = 32; off > 0; off >>= 1) {
            dp += __shfl_xor(dp, off);
            a2 += __shfl_xor(a2, off);
            b2 += __shfl_xor(b2, off);
        }
        if (tid == 0) {
            float n1 = fmaxf(sqrtf(a2), 1e-8f);
            float n2 = fmaxf(sqrtf(b2), 1e-8f);
            out[b] = dp / (n1 * n2) * 5.f;   // /TEMP
        }
    }
}

extern "C" void kernel_launch(void* const* d_in, const int* in_sizes, int n_in,
                              void* d_out, int out_size, void* d_ws, size_t ws_size,
                              hipStream_t stream) {
    const float* spt    = (const float*)d_in[0];
    const float* qry    = (const float*)d_in[1];
    const float* proj_w = (const float*)d_in[2];
    const float* proj_b = (const float*)d_in[3];
    const float* pos_x  = (const float*)d_in[4];
    const float* pos_y  = (const float*)d_in[5];
    const float* ln1_g  = (const float*)d_in[6];
    const float* ln1_b  = (const float*)d_in[7];
    const float* qkv_w  = (const float*)d_in[8];
    const float* qkv_b  = (const float*)d_in[9];
    const float* attn_w = (const float*)d_in[10];
    const float* attn_b = (const float*)d_in[11];
    const float* ln2_g  = (const float*)d_in[12];
    const float* ln2_b  = (const float*)d_in[13];
    const float* fc1_w  = (const float*)d_in[14];
    const float* fc1_b  = (const float*)d_in[15];
    const float* fc2_w  = (const float*)d_in[16];
    const float* fc2_b  = (const float*)d_in[17];
    const float* dec_w  = (const float*)d_in[18];
    const float* dec_b  = (const float*)d_in[19];
    float* ws  = (float*)d_ws;
    float* out = (float*)d_out;

    prep_spt<<<1, 128, 0, stream>>>(spt, proj_w, proj_b, ws);
    prep_qry<<<(NQN * 25 + 255) / 256, 256, 0, stream>>>(qry, proj_w, proj_b, ws);
    fused_kernel<<<NBATCH, 64, 0, stream>>>(qry, ws, pos_x, pos_y, qkv_w, qkv_b, attn_w, attn_b,
                                            ln1_g, ln1_b, ln2_g, ln2_b, fc1_w, fc1_b,
                                            fc2_w, fc2_b, dec_w, dec_b, out);
}